// Round 12
// baseline (438.799 us; speedup 1.0000x reference)
//
#include <hip/hip_runtime.h>
#include <math.h>

// ---------------- problem constants ----------------
constexpr int B_    = 64;
constexpr int NPG_  = 2048;
constexpr int N_    = B_ * NPG_;        // 131072
constexpr int E_    = N_ * 16;          // 2097152
constexpr int EPG_  = NPG_ * 16;        // 32768 edges per graph (contiguous)
constexpr int BPG_  = 8;                // CSR blocks per graph
constexpr int EPB_  = EPG_ / BPG_;      // 4096 edges per CSR block
constexpr int NCSRB = B_ * BPG_;        // 512 CSR blocks
constexpr int NF_   = 128;
constexpr int EF_   = 32;
constexpr int TLD_  = 97;
constexpr int K_    = 30;
constexpr int C1_   = 16;
constexpr int C2_   = 32;
constexpr int KW2_  = 5;
constexpr int P2_   = 15;
constexpr int U_    = 11;
constexpr int DENSE_= C2_ * U_;         // 352
constexpr int HID_  = 128;
constexpr int NCLS_ = 10;
constexpr int CATLD = 128;              // padded leading dim for cat[N][97]

__device__ __forceinline__ int cnt_of(float d) { return (int)(d + 0.5f) - 1; }

// XCD-aware bijective swizzle (grid divisible by 8)
__device__ __forceinline__ int xcd_swz(int bid, int nwg)
{
    int cpx = nwg >> 3;
    return (bid & 7) * cpx + (bid >> 3);
}

// ---------------- row_start from deg: 2-kernel scan of (deg-1) ----------------
__global__ __launch_bounds__(256) void k_scanA(const float* __restrict__ deg,
                                               int* __restrict__ bsum)
{
    const int t = threadIdx.x;
    const int base = blockIdx.x * 1024 + t * 4;
    int s = cnt_of(deg[base]) + cnt_of(deg[base + 1]) + cnt_of(deg[base + 2]) + cnt_of(deg[base + 3]);
#pragma unroll
    for (int d = 32; d > 0; d >>= 1) s += __shfl_down(s, d);
    __shared__ int ws[4];
    if ((t & 63) == 0) ws[t >> 6] = s;
    __syncthreads();
    if (t == 0) bsum[blockIdx.x] = ws[0] + ws[1] + ws[2] + ws[3];
}

__global__ __launch_bounds__(256) void k_scanB(const float* __restrict__ deg,
                                               const int* __restrict__ bsum,
                                               int* __restrict__ row_start)
{
    const int t = threadIdx.x;
    const int base = blockIdx.x * 1024 + t * 4;
    int c0 = cnt_of(deg[base + 0]);
    int c1 = cnt_of(deg[base + 1]);
    int c2 = cnt_of(deg[base + 2]);
    int c3 = cnt_of(deg[base + 3]);
    int s = c0 + c1 + c2 + c3;
    int lane = t & 63, w = t >> 6;
    int sc = s;
#pragma unroll
    for (int d = 1; d < 64; d <<= 1) {
        int v = __shfl_up(sc, d);
        if (lane >= d) sc += v;
    }
    __shared__ int wsum[4];
    __shared__ int soff;
    if (lane == 63) wsum[w] = sc;
    if (t == 0) {
        int a = 0;
        for (int j = 0; j < (int)blockIdx.x; j++) a += bsum[j];
        soff = a;
    }
    __syncthreads();
    int woff = soff;
    for (int k = 0; k < w; k++) woff += wsum[k];
    int excl = woff + sc - s;
    row_start[base + 0] = excl;
    row_start[base + 1] = excl + c0;
    row_start[base + 2] = excl + c0 + c1;
    row_start[base + 3] = excl + c0 + c1 + c2;
}

// ---------------- CSR build, atomic-free, XCD-co-located ----------------
// Block remap: g = bid%64, j = bid/64 -> all 8 blocks of graph g share bid%8,
// i.e. the same XCD; the graph's adj/cursor slices stay in one L2.
// Pass A: per-block histogram of its 4096 edges over the graph's 2048 rows.
__global__ __launch_bounds__(256) void k_hist(const int* __restrict__ erow,
                                              int* __restrict__ hist)
{
    const int bid = blockIdx.x, tid = threadIdx.x;
    const int g = bid & 63, j = bid >> 6;
    const int lb = g * BPG_ + j;                  // logical block index
    const int base_e = g * EPG_ + j * EPB_;
    const int base_n = g * NPG_;
    __shared__ int h[NPG_];
#pragma unroll
    for (int q = 0; q < NPG_ / 256; q++) h[tid + q * 256] = 0;
    __syncthreads();
#pragma unroll
    for (int q = 0; q < EPB_ / 256; q++)
        atomicAdd(&h[erow[base_e + tid + q * 256] - base_n], 1);
    __syncthreads();
#pragma unroll
    for (int q = 0; q < NPG_ / 256; q++)
        hist[lb * NPG_ + tid + q * 256] = h[tid + q * 256];
}

// Pass B: cursor_blk[lb][r] = row_start[row] + sum_{b'<b} hist[g*8+b'][r]
__global__ __launch_bounds__(256) void k_scanblk(const int* __restrict__ hist,
                                                 const int* __restrict__ row_start,
                                                 int* __restrict__ cursor_blk)
{
    int i = blockIdx.x * 256 + threadIdx.x;     // N threads (global row)
    int g = i >> 11, r = i & 2047;
    int acc = row_start[i];
#pragma unroll
    for (int b = 0; b < BPG_; b++) {
        int idx = (g * BPG_ + b) * NPG_ + r;
        int c = hist[idx];
        cursor_blk[idx] = acc;
        acc += c;
    }
}

// Pass C: fill via LDS cursors — zero global atomics; split adjc/adje.
__global__ __launch_bounds__(256) void k_fillc(const int* __restrict__ erow,
                                               const int* __restrict__ ecol,
                                               const int* __restrict__ cursor_blk,
                                               int* __restrict__ adjc,
                                               int* __restrict__ adje)
{
    const int bid = blockIdx.x, tid = threadIdx.x;
    const int g = bid & 63, j = bid >> 6;
    const int lb = g * BPG_ + j;
    const int base_e = g * EPG_ + j * EPB_;
    const int base_n = g * NPG_;
    __shared__ int cur[NPG_];
#pragma unroll
    for (int q = 0; q < NPG_ / 256; q++)
        cur[tid + q * 256] = cursor_blk[lb * NPG_ + tid + q * 256];
    __syncthreads();
#pragma unroll
    for (int q = 0; q < EPB_ / 256; q++) {
        int e = base_e + tid + q * 256;
        int r = erow[e] - base_n;
        int slot = atomicAdd(&cur[r], 1);
        adjc[slot] = ecol[e];
        adje[slot] = e;
    }
}

// ---------------- e2n gather: coop index load + shuffle broadcast, nontemporal ef ----------------
__global__ __launch_bounds__(256) void k_e2n_gather(const float* __restrict__ ef,
                                                    const int* __restrict__ row_start,
                                                    const float* __restrict__ deg,
                                                    const int* __restrict__ adje,
                                                    float* __restrict__ e2n)
{
    int gid = xcd_swz(blockIdx.x, gridDim.x) * 256 + threadIdx.x;   // N*32 threads
    int i = gid >> 5, o = gid & 31;
    int s = row_start[i];
    int n = cnt_of(deg[i]);
    float a = 0.f;
    for (int base = 0; base < n; base += 32) {
        int m = n - base; int mi = (m > 32) ? 32 : m;   // >= 1
        int idx = adje[s + base + ((o < mi) ? o : (mi - 1))];
#pragma unroll
        for (int k = 0; k < 32; k++) {
            int e = __shfl(idx, k, 32);
            float w = (k < mi) ? 1.f : 0.f;
            a += w * __builtin_nontemporal_load(&ef[(long)e * EF_ + o]);
        }
    }
    e2n[gid] = a;
}

// ---------------- layer 0 GEMM: p = [nf | e2n] @ W0^T ----------------
__global__ __launch_bounds__(256) void k_gemm0(const float* __restrict__ nf,
                                               const float* __restrict__ e2n,
                                               const float* __restrict__ W0,
                                               float* __restrict__ p)
{
    __shared__ float Ws[32 * 160];
    for (int t = threadIdx.x; t < 32 * 160; t += 256) Ws[t] = W0[t];
    __syncthreads();
    int i = blockIdx.x * 256 + threadIdx.x;
    float acc[32];
#pragma unroll
    for (int o = 0; o < 32; o++) acc[o] = 0.f;
    const float4* row  = reinterpret_cast<const float4*>(nf  + (long)i * NF_);
    const float4* row2 = reinterpret_cast<const float4*>(e2n + (long)i * EF_);
    const float4* Ws4  = reinterpret_cast<const float4*>(Ws);
    for (int d4 = 0; d4 < NF_ / 4; ++d4) {
        float4 v = row[d4];
#pragma unroll
        for (int o = 0; o < 32; o++) {
            float4 w = Ws4[o * 40 + d4];
            acc[o] += v.x * w.x + v.y * w.y + v.z * w.z + v.w * w.w;
        }
    }
#pragma unroll
    for (int d4 = 0; d4 < EF_ / 4; ++d4) {
        float4 v = row2[d4];
#pragma unroll
        for (int o = 0; o < 32; o++) {
            float4 w = Ws4[o * 40 + 32 + d4];
            acc[o] += v.x * w.x + v.y * w.y + v.z * w.z + v.w * w.w;
        }
    }
    float4* p4 = reinterpret_cast<float4*>(p + (long)i * 32);
#pragma unroll
    for (int o4 = 0; o4 < 8; o4++)
        p4[o4] = make_float4(acc[o4*4], acc[o4*4+1], acc[o4*4+2], acc[o4*4+3]);
}

// ---------------- fused: gather + tanh + NEXT-layer projection ----------------
__global__ __launch_bounds__(256) void k_gather_proj(const int* __restrict__ row_start,
                                                     const int* __restrict__ adjc,
                                                     const float* __restrict__ deg,
                                                     const float* __restrict__ p_in,
                                                     const float* __restrict__ b,
                                                     float* __restrict__ cat, int out_off,
                                                     const float* __restrict__ Wn,
                                                     float* __restrict__ p_out)
{
    __shared__ float WT[32 * 32];
    for (int idx = threadIdx.x; idx < 1024; idx += 256) {
        int k = idx >> 5, o = idx & 31;
        WT[idx] = Wn[o * 32 + k];
    }
    __syncthreads();
    int gid = xcd_swz(blockIdx.x, gridDim.x) * 256 + threadIdx.x;   // N*32 threads
    int i = gid >> 5, o = gid & 31;
    int s = row_start[i];
    float dg = deg[i];
    int n = cnt_of(dg);
    float a = p_in[gid];
    for (int base = 0; base < n; base += 32) {
        int m = n - base; int mi = (m > 32) ? 32 : m;
        int idx = adjc[s + base + ((o < mi) ? o : (mi - 1))];
#pragma unroll
        for (int k = 0; k < 32; k++) {
            int c = __shfl(idx, k, 32);
            float w = (k < mi) ? 1.f : 0.f;
            a += w * p_in[(long)c * 32 + o];
        }
    }
    float t = tanhf((a + b[o]) / dg);
    cat[(long)i * CATLD + out_off + o] = t;
    float acc = 0.f;
#pragma unroll
    for (int k = 0; k < 32; k++)
        acc += __shfl(t, k, 32) * WT[k * 32 + o];
    p_out[(long)i * 32 + o] = acc;
}

// ---------------- gather + tanh + 1-wide W3 projection (layer 2) ----------------
__global__ __launch_bounds__(256) void k_gather_act32(const int* __restrict__ row_start,
                                                      const int* __restrict__ adjc,
                                                      const float* __restrict__ deg,
                                                      const float* __restrict__ p,
                                                      const float* __restrict__ b,
                                                      float* __restrict__ cat, int out_off,
                                                      const float* __restrict__ W3,
                                                      float* __restrict__ p1)
{
    int gid = xcd_swz(blockIdx.x, gridDim.x) * 256 + threadIdx.x;   // N*32 threads
    int i = gid >> 5, o = gid & 31;
    int s = row_start[i];
    float dg = deg[i];
    int n = cnt_of(dg);
    float a = p[gid];
    for (int base = 0; base < n; base += 32) {
        int m = n - base; int mi = (m > 32) ? 32 : m;
        int idx = adjc[s + base + ((o < mi) ? o : (mi - 1))];
#pragma unroll
        for (int k = 0; k < 32; k++) {
            int c = __shfl(idx, k, 32);
            float w = (k < mi) ? 1.f : 0.f;
            a += w * p[(long)c * 32 + o];
        }
    }
    float t = tanhf((a + b[o]) / dg);
    cat[(long)i * CATLD + out_off + o] = t;
    float r = t * W3[o];
#pragma unroll
    for (int sft = 16; sft > 0; sft >>= 1) r += __shfl_xor(r, sft, 32);
    if (o == 0) p1[i] = r;
}

// ---------------- fused tail: layer-3 pool/act + top-K + conv/MLP head ----------------
// One block per graph. t3 values computed into LDS (no cat col-96 round-trip);
// Pm[k][96] captured from the selection value itself.
__global__ __launch_bounds__(256) void k_tail(
    const int* __restrict__ row_start,
    const int* __restrict__ adjc,
    const float* __restrict__ deg,
    const float* __restrict__ p1,
    const float* __restrict__ b3,
    const float* __restrict__ cat,
    const float* __restrict__ Wc1, const float* __restrict__ bc1,
    const float* __restrict__ Wc2, const float* __restrict__ bc2,
    const float* __restrict__ Wh,  const float* __restrict__ bh,
    const float* __restrict__ Wo,  const float* __restrict__ bo,
    float* __restrict__ out)
{
    const int g = blockIdx.x, tid = threadIdx.x;
    __shared__ float vals[NPG_];
    __shared__ int   sel[K_];
    __shared__ float selv[K_];
    __shared__ float Pm[K_][TLD_];
    __shared__ float y1[C1_][K_];
    __shared__ float y2[C1_][P2_];
    __shared__ float dd[DENSE_];
    __shared__ float h1s[HID_];
    __shared__ float zz[NCLS_];
    const long gbase = (long)g * NPG_;
    const float bb = b3[0];

    // phase 1: layer-3 gather + tanh into LDS (chunk-8 MLP)
    for (int j = tid; j < NPG_; j += 256) {
        int i = (int)gbase + j;
        int s = row_start[i];
        float dg = deg[i];
        int n = cnt_of(dg);
        float a = p1[i];
        int k = 0;
        for (; k + 8 <= n; k += 8) {
            int c0 = adjc[s + k + 0], c1 = adjc[s + k + 1], c2 = adjc[s + k + 2], c3 = adjc[s + k + 3];
            int c4 = adjc[s + k + 4], c5 = adjc[s + k + 5], c6 = adjc[s + k + 6], c7 = adjc[s + k + 7];
            float v0 = p1[c0], v1 = p1[c1], v2 = p1[c2], v3 = p1[c3];
            float v4 = p1[c4], v5 = p1[c5], v6 = p1[c6], v7 = p1[c7];
            a += ((v0 + v1) + (v2 + v3)) + ((v4 + v5) + (v6 + v7));
        }
        for (; k < n; k++) a += p1[adjc[s + k]];
        vals[j] = tanhf((a + bb) / dg);
    }
    __syncthreads();

    // phase 2: top-K, ties -> lower index; wave 0 only, no barriers
    if (tid < 64) {
        for (int k = 0; k < K_; k++) {
            float bv = -INFINITY; int bj = NPG_;
#pragma unroll
            for (int m = 0; m < 32; m++) {
                int j = m * 64 + tid;               // ascending j per lane -> strict > keeps lowest
                float v = vals[j];
                if (v > bv) { bv = v; bj = j; }
            }
#pragma unroll
            for (int s = 32; s > 0; s >>= 1) {
                float ov = __shfl_xor(bv, s);
                int   oj = __shfl_xor(bj, s);
                if (ov > bv || (ov == bv && oj < bj)) { bv = ov; bj = oj; }
            }
            if (tid == 0) { sel[k] = bj; selv[k] = bv; vals[bj] = -INFINITY; }
        }
    }
    __syncthreads();

    // phase 3: gather selected rows (cols 0..95 from cat, col 96 from selv)
    for (int t = tid; t < K_ * TLD_; t += 256) {
        int k = t / TLD_, d = t % TLD_;
        Pm[k][d] = (d < 96) ? cat[(gbase + sel[k]) * CATLD + d] : selv[k];
    }
    __syncthreads();

    for (int t = tid; t < C1_ * K_; t += 256) {
        int c = t / K_, k = t % K_;
        float a = bc1[c];
        for (int d = 0; d < TLD_; d++) a += Pm[k][d] * Wc1[c * TLD_ + d];
        y1[c][k] = fmaxf(a, 0.f);
    }
    __syncthreads();

    for (int t = tid; t < C1_ * P2_; t += 256) {
        int c = t / P2_, u = t % P2_;
        y2[c][u] = fmaxf(y1[c][2 * u], y1[c][2 * u + 1]);
    }
    __syncthreads();

    for (int t = tid; t < C2_ * U_; t += 256) {
        int c2 = t / U_, u = t % U_;
        float a = bc2[c2];
        for (int c = 0; c < C1_; c++)
#pragma unroll
            for (int w = 0; w < KW2_; w++)
                a += y2[c][u + w] * Wc2[(c2 * C1_ + c) * KW2_ + w];
        dd[t] = fmaxf(a, 0.f);
    }
    __syncthreads();

    if (tid < HID_) {
        float a = bh[tid];
        for (int i = 0; i < DENSE_; i++) a += dd[i] * Wh[tid * DENSE_ + i];
        h1s[tid] = fmaxf(a, 0.f);
    }
    __syncthreads();

    if (tid < NCLS_) {
        float a = bo[tid];
        for (int j = 0; j < HID_; j++) a += h1s[j] * Wo[tid * HID_ + j];
        zz[tid] = a;
    }
    __syncthreads();

    if (tid == 0) {
        float m = zz[0];
        for (int c = 1; c < NCLS_; c++) m = fmaxf(m, zz[c]);
        float s = 0.f;
        for (int c = 0; c < NCLS_; c++) s += expf(zz[c] - m);
        float lse = m + logf(s);
        for (int c = 0; c < NCLS_; c++) out[g * NCLS_ + c] = zz[c] - lse;
    }
}

// ---------------- host launch ----------------
extern "C" void kernel_launch(void* const* d_in, const int* in_sizes, int n_in,
                              void* d_out, int out_size, void* d_ws, size_t ws_size,
                              hipStream_t stream)
{
    const float* nf  = (const float*)d_in[0];
    const float* ef  = (const float*)d_in[1];
    const float* deg = (const float*)d_in[2];
    const float* W0  = (const float*)d_in[3];  const float* b0  = (const float*)d_in[4];
    const float* W1  = (const float*)d_in[5];  const float* b1  = (const float*)d_in[6];
    const float* W2  = (const float*)d_in[7];  const float* b2  = (const float*)d_in[8];
    const float* W3  = (const float*)d_in[9];  const float* b3  = (const float*)d_in[10];
    const float* Wc1 = (const float*)d_in[11]; const float* bc1 = (const float*)d_in[12];
    const float* Wc2 = (const float*)d_in[13]; const float* bc2 = (const float*)d_in[14];
    const float* Wh  = (const float*)d_in[15]; const float* bh  = (const float*)d_in[16];
    const float* Wo  = (const float*)d_in[17]; const float* bo  = (const float*)d_in[18];
    const int* erow  = (const int*)d_in[19];
    const int* ecol  = (const int*)d_in[20];
    float* out = (float*)d_out;

    // ---- workspace layout ----
    char* wsb = (char*)d_ws;
    float* e2n       = (float*)wsb;                       wsb += (size_t)N_ * 32 * 4;   // 16 MB
    float* pA        = (float*)wsb;                       wsb += (size_t)N_ * 32 * 4;   // 16 MB
    float* pB        = (float*)wsb;                       wsb += (size_t)N_ * 32 * 4;   // 16 MB
    float* cat       = (float*)wsb;                       wsb += (size_t)N_ * CATLD * 4;// 64 MB
    float* p1        = (float*)wsb;                       wsb += (size_t)N_ * 4;        // 0.5 MB
    int*   row_start = (int*)wsb;                         wsb += (size_t)N_ * 4;
    int*   bsum      = (int*)wsb;                         wsb += 128 * 4;
    int*   adjc      = (int*)wsb;                         wsb += (size_t)E_ * 4;        // 8 MB
    int*   adje      = (int*)wsb;                         /* 8 MB */

    // hist / cursor_blk (4 MB each) overlay pA / pB — both dead until k_gemm0 / k_gather_proj
    int* hist       = (int*)pA;
    int* cursor_blk = (int*)pB;

    // ---- row_start from deg ----
    k_scanA<<<N_ / 1024, 256, 0, stream>>>(deg, bsum);
    k_scanB<<<N_ / 1024, 256, 0, stream>>>(deg, bsum, row_start);

    // ---- CSR build, atomic-free, XCD-co-located ----
    k_hist<<<NCSRB, 256, 0, stream>>>(erow, hist);
    k_scanblk<<<N_ / 256, 256, 0, stream>>>(hist, row_start, cursor_blk);
    k_fillc<<<NCSRB, 256, 0, stream>>>(erow, ecol, cursor_blk, adjc, adje);

    // ---- e2n via gather ----
    k_e2n_gather<<<N_ * 32 / 256, 256, 0, stream>>>(ef, row_start, deg, adje, e2n);

    // ---- layer 0 projection ----
    k_gemm0<<<N_ / 256, 256, 0, stream>>>(nf, e2n, W0, pA);
    // ---- layer 0 pool/act + W1 projection ----
    k_gather_proj<<<N_ * 32 / 256, 256, 0, stream>>>(row_start, adjc, deg, pA, b0, cat, 0, W1, pB);
    // ---- layer 1 pool/act + W2 projection ----
    k_gather_proj<<<N_ * 32 / 256, 256, 0, stream>>>(row_start, adjc, deg, pB, b1, cat, 32, W2, pA);
    // ---- layer 2 pool/act + W3 projection (1-wide) ----
    k_gather_act32<<<N_ * 32 / 256, 256, 0, stream>>>(row_start, adjc, deg, pA, b2, cat, 64, W3, p1);

    // ---- fused layer-3 + sortpooling + head ----
    k_tail<<<B_, 256, 0, stream>>>(row_start, adjc, deg, p1, b3, cat,
                                   Wc1, bc1, Wc2, bc2, Wh, bh, Wo, bo, out);
}